// Round 1
// baseline (313.433 us; speedup 1.0000x reference)
//
#include <hip/hip_runtime.h>
#include <math.h>

// Problem constants (from reference setup_inputs):
//   inputs: [B=64, I=2048, P=16] f32
//   W:      [I=2048, J=32, P=16, D=32] f32
//   bias:   [1, I, J, 1, 1] f32
//   out:    [B=64, J=32, D=32] f32
#define I_CAP 2048
#define P_DIM 16
#define J_CAP 32
#define D_DIM 32
#define B_SZ  64
#define I_CHUNKS 16
#define I_PER (I_CAP / I_CHUNKS) // 128

// ---------------- k1: c[i][j] = softmax over j of bias[i][j] ----------------
// grid 256 x 256 threads covers I*J = 65536; lanes 0..31 of each 32-group share one i.
__global__ __launch_bounds__(256) void caps_softmax_k(const float* __restrict__ bias,
                                                      float* __restrict__ c_tab) {
    int tid = blockIdx.x * 256 + threadIdx.x;   // = i*32 + j
    float x = bias[tid];
    float m = x;
#pragma unroll
    for (int k = 16; k >= 1; k >>= 1) m = fmaxf(m, __shfl_xor(m, k));
    float e = expf(x - m);
    float s = e;
#pragma unroll
    for (int k = 16; k >= 1; k >>= 1) s += __shfl_xor(s, k);
    c_tab[tid] = e / s;
}

// ---------------- k2: s[b,j,d] += sum_{i in chunk, p} in[b,i,p]*c[i,j]*W[i,j,p,d] ----
// grid = I_CHUNKS*J_CAP = 512 blocks, 512 threads.
// block -> (i-chunk, j). thread -> (b = t>>3, d4 = (t&7)*4).
// Per wave, a W load instr touches one 128B line (8 distinct float4, 8-way b broadcast).
__global__ __launch_bounds__(512) void caps_main_k(const float* __restrict__ inputs,
                                                   const float* __restrict__ W,
                                                   const float* __restrict__ c_tab,
                                                   float* __restrict__ s_accum) {
    const int t  = threadIdx.x;
    const int d4 = (t & 7) * 4;
    const int b  = t >> 3;
    const int jb = blockIdx.x & 31;
    const int ic = blockIdx.x >> 5;

    const float* inp = inputs + b * (I_CAP * P_DIM) + (ic * I_PER) * P_DIM;
    const float* wp  = W + ((ic * I_PER) * J_CAP + jb) * (P_DIM * D_DIM) + d4;
    const float* cp  = c_tab + (ic * I_PER) * J_CAP + jb;

    float acc0 = 0.f, acc1 = 0.f, acc2 = 0.f, acc3 = 0.f;

    for (int ii = 0; ii < I_PER; ++ii) {
        // inputs[b, i, 0..15]
        const float4* ain = (const float4*)inp;
        float4 a0 = ain[0], a1 = ain[1], a2 = ain[2], a3 = ain[3];
        float a[16];
        a[0]=a0.x;  a[1]=a0.y;  a[2]=a0.z;  a[3]=a0.w;
        a[4]=a1.x;  a[5]=a1.y;  a[6]=a1.z;  a[7]=a1.w;
        a[8]=a2.x;  a[9]=a2.y;  a[10]=a2.z; a[11]=a2.w;
        a[12]=a3.x; a[13]=a3.y; a[14]=a3.z; a[15]=a3.w;

        float cj = cp[0];   // uniform within block -> scalar load

        float u0 = 0.f, u1 = 0.f, u2 = 0.f, u3 = 0.f;
#pragma unroll
        for (int p = 0; p < P_DIM; ++p) {
            float4 w = *(const float4*)(wp + p * D_DIM);
            u0 += a[p] * w.x;
            u1 += a[p] * w.y;
            u2 += a[p] * w.z;
            u3 += a[p] * w.w;
        }
        acc0 += cj * u0;
        acc1 += cj * u1;
        acc2 += cj * u2;
        acc3 += cj * u3;

        inp += P_DIM;
        wp  += J_CAP * P_DIM * D_DIM;   // next i
        cp  += J_CAP;
    }

    const int o = (b * J_CAP + jb) * D_DIM + d4;
    atomicAdd(&s_accum[o + 0], acc0);
    atomicAdd(&s_accum[o + 1], acc1);
    atomicAdd(&s_accum[o + 2], acc2);
    atomicAdd(&s_accum[o + 3], acc3);
}

// ---------------- k3: squash per (b,j) row of 32 d's ----------------
// grid 256 x 256 covers 65536 = B*J*D; each 32-lane group is one (b,j) row.
__global__ __launch_bounds__(256) void caps_squash_k(const float* __restrict__ s_accum,
                                                     float* __restrict__ out) {
    int tid = blockIdx.x * 256 + threadIdx.x;
    float v = s_accum[tid];
    float sq = v * v;
#pragma unroll
    for (int k = 16; k >= 1; k >>= 1) sq += __shfl_xor(sq, k);
    // scale = s2 / (1+s2) / sqrt(s2)  (exactly as reference)
    float scale = sq / (1.0f + sq) / sqrtf(sq);
    out[tid] = v * scale;
}

extern "C" void kernel_launch(void* const* d_in, const int* in_sizes, int n_in,
                              void* d_out, int out_size, void* d_ws, size_t ws_size,
                              hipStream_t stream) {
    const float* inputs = (const float*)d_in[0];
    const float* W      = (const float*)d_in[1];
    const float* bias   = (const float*)d_in[2];
    float* out = (float*)d_out;

    float* c_tab   = (float*)d_ws;          // 65536 f32 = 256 KB
    float* s_accum = c_tab + I_CAP * J_CAP; // 65536 f32 = 256 KB

    hipMemsetAsync(s_accum, 0, (size_t)B_SZ * J_CAP * D_DIM * sizeof(float), stream);
    caps_softmax_k<<<dim3(256), dim3(256), 0, stream>>>(bias, c_tab);
    caps_main_k<<<dim3(I_CHUNKS * J_CAP), dim3(512), 0, stream>>>(inputs, W, c_tab, s_accum);
    caps_squash_k<<<dim3((B_SZ * J_CAP * D_DIM) / 256), dim3(256), 0, stream>>>(s_accum, out);
}

// Round 2
// 108.891 us; speedup vs baseline: 2.8784x; 2.8784x over previous
//
#include <hip/hip_runtime.h>
#include <math.h>

// inputs: [B=64, I=2048, P=16] f32
// W:      [I=2048, J=32, P=16, D=32] f32
// bias:   [1, I, J, 1, 1] f32
// out:    [B=64, J=32, D=32] f32
#define I_CAP 2048
#define P_DIM 16
#define J_CAP 32
#define D_DIM 32
#define B_SZ  64
#define KC    32            // k-chunks over i  -> grid = 32 j * 32 kc = 1024 blocks
#define IPB   (I_CAP / KC)  // 64 i per block
#define IPW   (IPB / 4)     // 16 i per wave

// async global->LDS, 16B per lane; LDS dest = uniform base + lane*16 (linear)
#define GLOAD_LDS16(gp, lp)                                                     \
    __builtin_amdgcn_global_load_lds(                                           \
        (const __attribute__((address_space(1))) void*)(gp),                    \
        (__attribute__((address_space(3))) void*)(lp), 16, 0, 0)

// ---------------- k0: c[i][j] = softmax over j of bias[i][j] ----------------
__global__ __launch_bounds__(256) void caps_softmax_k(const float* __restrict__ bias,
                                                      float* __restrict__ c_tab) {
    int tid = blockIdx.x * 256 + threadIdx.x;   // = i*32 + j
    float x = bias[tid];
    float m = x;
#pragma unroll
    for (int k = 16; k >= 1; k >>= 1) m = fmaxf(m, __shfl_xor(m, k));
    float e = expf(x - m);
    float s = e;
#pragma unroll
    for (int k = 16; k >= 1; k >>= 1) s += __shfl_xor(s, k);
    c_tab[tid] = e / s;
}

// ---------------- k1: main GEMM ----------------
// block = 256 thr = 4 waves, all on one j; wave w owns i-range [kc*64 + w*16, +16).
// Per wave: private double-buffered LDS {W: 512 f, A^T(scaled by c): 1024 f}.
// Thread tile: 4b x 8d (32 acc). No barriers in main loop (per-wave buffers).
__global__ __launch_bounds__(256) void caps_main_k(const float* __restrict__ inputs,
                                                   const float* __restrict__ W,
                                                   const float* __restrict__ c_tab,
                                                   float* __restrict__ s_accum) {
    __shared__ float lds[12288];  // 48KB = 4 waves * 2 bufs * 1536 floats
    const int t    = threadIdx.x;
    const int lane = t & 63;
    const int wv   = t >> 6;            // 0..3
    const int j    = blockIdx.x & 31;
    const int kc   = blockIdx.x >> 5;

    const int bg   = lane >> 2;         // 0..15  (compute: b-group)
    const int dg   = lane & 3;          // 0..3   (compute: d-group)
    const int bsub = lane >> 2;         // staging: b sub-index
    const int pq   = lane & 3;          // staging: p quad

    const int i0    = kc * IPB + wv * IPW;
    const int lbase = wv * 3072;        // per-wave LDS region (2 x 1536 floats)

    float acc[4][8];
#pragma unroll
    for (int x = 0; x < 4; ++x)
#pragma unroll
        for (int y = 0; y < 8; ++y) acc[x][y] = 0.f;

    float4 areg[4];
    float  cnext;

    // ---- prologue: stage round 0 into buf 0 ----
    {
        const int i = i0;
        const float* wsrc = W + ((size_t)(i * J_CAP + j) << 9);
        float* wdst = &lds[lbase];
        GLOAD_LDS16(wsrc + lane * 4, wdst);
        GLOAD_LDS16(wsrc + 256 + lane * 4, wdst + 256);
#pragma unroll
        for (int n = 0; n < 4; ++n) {
            const int b = n * 16 + bsub;
            areg[n] = *(const float4*)(inputs + (((size_t)b * I_CAP + i) << 4) + pq * 4);
        }
        cnext = c_tab[i * J_CAP + j];
    }
    asm volatile("s_waitcnt vmcnt(0)" ::: "memory");
    {
        float* adst = &lds[lbase + 512];
#pragma unroll
        for (int n = 0; n < 4; ++n) {
            const int b = n * 16 + bsub;
            adst[(pq * 4 + 0) * 64 + b] = areg[n].x * cnext;
            adst[(pq * 4 + 1) * 64 + b] = areg[n].y * cnext;
            adst[(pq * 4 + 2) * 64 + b] = areg[n].z * cnext;
            adst[(pq * 4 + 3) * 64 + b] = areg[n].w * cnext;
        }
    }

    // ---- main loop over i (per-wave, barrier-free) ----
    for (int r = 0; r < IPW; ++r) {
        const int pb = r & 1;
        if (r + 1 < IPW) {   // issue next-round stage (hidden under compute)
            const int i = i0 + r + 1;
            const float* wsrc = W + ((size_t)(i * J_CAP + j) << 9);
            float* wdst = &lds[lbase + (pb ^ 1) * 1536];
            GLOAD_LDS16(wsrc + lane * 4, wdst);
            GLOAD_LDS16(wsrc + 256 + lane * 4, wdst + 256);
#pragma unroll
            for (int n = 0; n < 4; ++n) {
                const int b = n * 16 + bsub;
                areg[n] = *(const float4*)(inputs + (((size_t)b * I_CAP + i) << 4) + pq * 4);
            }
            cnext = c_tab[i * J_CAP + j];
        }
        // compute round r from buf pb
        const float* wb = &lds[lbase + pb * 1536];
        const float* ab = wb + 512;
#pragma unroll
        for (int kk = 0; kk < P_DIM; ++kk) {
            float4 av = *(const float4*)(ab + kk * 64 + bg * 4);
            float4 w0 = *(const float4*)(wb + kk * 32 + dg * 8);
            float4 w1 = *(const float4*)(wb + kk * 32 + dg * 8 + 4);
            float a4[4] = {av.x, av.y, av.z, av.w};
            float w8[8] = {w0.x, w0.y, w0.z, w0.w, w1.x, w1.y, w1.z, w1.w};
#pragma unroll
            for (int x = 0; x < 4; ++x)
#pragma unroll
                for (int y = 0; y < 8; ++y) acc[x][y] = fmaf(a4[x], w8[y], acc[x][y]);
        }
        // drain staging loads (incl. global_load_lds into next buf), then write A^T
        asm volatile("s_waitcnt vmcnt(0)" ::: "memory");
        if (r + 1 < IPW) {
            float* adst = &lds[lbase + (pb ^ 1) * 1536 + 512];
#pragma unroll
            for (int n = 0; n < 4; ++n) {
                const int b = n * 16 + bsub;
                adst[(pq * 4 + 0) * 64 + b] = areg[n].x * cnext;
                adst[(pq * 4 + 1) * 64 + b] = areg[n].y * cnext;
                adst[(pq * 4 + 2) * 64 + b] = areg[n].z * cnext;
                adst[(pq * 4 + 3) * 64 + b] = areg[n].w * cnext;
            }
        }
    }

    // ---- block reduction over the 4 waves, then one atomic set ----
    __syncthreads();   // all waves done with staging LDS
    {
        float* red = lds;  // reuse: red[wv*2048 + b*32 + d]
#pragma unroll
        for (int x = 0; x < 4; ++x) {
            float4 v0 = {acc[x][0], acc[x][1], acc[x][2], acc[x][3]};
            float4 v1 = {acc[x][4], acc[x][5], acc[x][6], acc[x][7]};
            *(float4*)(red + wv * 2048 + (bg * 4 + x) * 32 + dg * 8)     = v0;
            *(float4*)(red + wv * 2048 + (bg * 4 + x) * 32 + dg * 8 + 4) = v1;
        }
    }
    __syncthreads();
    {
        const float* red = lds;
#pragma unroll
        for (int q = 0; q < 2; ++q) {
            const int o = t * 8 + q * 4;     // 0..2044, b = o>>5, d = o&31
            float4 s0 = *(const float4*)(red + o);
            float4 s1 = *(const float4*)(red + 2048 + o);
            float4 s2 = *(const float4*)(red + 4096 + o);
            float4 s3 = *(const float4*)(red + 6144 + o);
            const int b = o >> 5, d = o & 31;
            float* dst = s_accum + (size_t)b * (J_CAP * D_DIM) + j * D_DIM + d;
            atomicAdd(dst + 0, s0.x + s1.x + s2.x + s3.x);
            atomicAdd(dst + 1, s0.y + s1.y + s2.y + s3.y);
            atomicAdd(dst + 2, s0.z + s1.z + s2.z + s3.z);
            atomicAdd(dst + 3, s0.w + s1.w + s2.w + s3.w);
        }
    }
}

// ---------------- k2: squash per (b,j) row of 32 d's ----------------
__global__ __launch_bounds__(256) void caps_squash_k(const float* __restrict__ s_accum,
                                                     float* __restrict__ out) {
    int tid = blockIdx.x * 256 + threadIdx.x;
    float v = s_accum[tid];
    float sq = v * v;
#pragma unroll
    for (int k = 16; k >= 1; k >>= 1) sq += __shfl_xor(sq, k);
    float scale = sq / (1.0f + sq) / sqrtf(sq);
    out[tid] = v * scale;
}

extern "C" void kernel_launch(void* const* d_in, const int* in_sizes, int n_in,
                              void* d_out, int out_size, void* d_ws, size_t ws_size,
                              hipStream_t stream) {
    const float* inputs = (const float*)d_in[0];
    const float* W      = (const float*)d_in[1];
    const float* bias   = (const float*)d_in[2];
    float* out = (float*)d_out;

    float* c_tab   = (float*)d_ws;           // 65536 f32 = 256 KB
    float* s_accum = c_tab + I_CAP * J_CAP;  // 65536 f32 = 256 KB

    hipMemsetAsync(s_accum, 0, (size_t)B_SZ * J_CAP * D_DIM * sizeof(float), stream);
    caps_softmax_k<<<dim3(256), dim3(256), 0, stream>>>(bias, c_tab);
    caps_main_k<<<dim3(J_CAP * KC), dim3(256), 0, stream>>>(inputs, W, c_tab, s_accum);
    caps_squash_k<<<dim3((B_SZ * J_CAP * D_DIM) / 256), dim3(256), 0, stream>>>(s_accum, out);
}

// Round 3
// 52.785 us; speedup vs baseline: 5.9380x; 2.0629x over previous
//
#include <hip/hip_runtime.h>
#include <hip/hip_bf16.h>
#include <math.h>

// inputs: [B=64, I=2048, P=16] f32
// W:      [I=2048, J=32, P=16, D=32] f32
// bias:   [1, I, J, 1, 1] f32
// out:    [B=64, J=32, D=32] f32
#define I_CAP 2048
#define P_DIM 16
#define J_CAP 32
#define D_DIM 32
#define B_SZ  64
#define KC    16            // i-chunks -> grid = 32 j * 16 = 512 blocks
#define IPB   (I_CAP / KC)  // 128 i per block
#define IPW   (IPB / 4)     // 32 i per wave

typedef __attribute__((ext_vector_type(8)))  short short8_t;
typedef __attribute__((ext_vector_type(16))) float f32x16;

__device__ __forceinline__ short f2bf(float f) {
    __hip_bfloat16 h = __float2bfloat16(f);   // RNE
    return __builtin_bit_cast(short, h);
}

// ---------------- k0: c[i][j] = softmax over j of bias[i][j] ----------------
__global__ __launch_bounds__(256) void caps_softmax_k(const float* __restrict__ bias,
                                                      float* __restrict__ c_tab) {
    int tid = blockIdx.x * 256 + threadIdx.x;   // = i*32 + j
    float x = bias[tid];
    float m = x;
#pragma unroll
    for (int k = 16; k >= 1; k >>= 1) m = fmaxf(m, __shfl_xor(m, k));
    float e = expf(x - m);
    float s = e;
#pragma unroll
    for (int k = 16; k >= 1; k >>= 1) s += __shfl_xor(s, k);
    c_tab[tid] = e / s;
}

// ---------------- k1: main GEMM via bf16 MFMA ----------------
// s[b, j*32+d] = sum_{i,p} inputs[b,i,p] * (c[i,j]*W[i,j,p,d])
// One 32x32x16 MFMA k-step == one (i,j): B = c*W[i,j,:,:], A = inputs[:,i,:].
// block = 4 waves, same j, disjoint i-subranges. No LDS in main loop.
// B-frag: lane l -> n=d=(l&31), k=p=(l>>5)*8+e   (k-permutation-safe: A uses same map)
// A-frag: lane l -> m=b=(l&31)+32*mf, k=p=(l>>5)*8+e  -> 8 consecutive fp32
// C/D:    b = mf*32 + (reg&3) + 8*(reg>>2) + 4*(l>>5), d = l&31   [m74/m101]
__global__ __launch_bounds__(256) void caps_main_k(const float* __restrict__ inputs,
                                                   const float* __restrict__ W,
                                                   const float* __restrict__ c_tab,
                                                   float* __restrict__ s_accum) {
    __shared__ float red[4 * 2048];   // 32 KB: per-wave [64 b][32 d]
    const int t  = threadIdx.x;
    const int l  = t & 63;
    const int wv = t >> 6;
    const int j  = blockIdx.x & 31;
    const int kc = blockIdx.x >> 5;
    const int g  = l >> 5;     // p-half selector (k-group)
    const int dn = l & 31;     // d for B-frag, b for A-frag

    const int i0 = kc * IPB + wv * IPW;

    const float* wlane  = W + (((size_t)(i0 * J_CAP + j)) << 9) + g * 256 + dn;
    const float* alane0 = inputs + ((size_t)dn << 15) + (size_t)i0 * 16 + g * 8;
    const float* alane1 = alane0 + ((size_t)32 << 15);
    const float* cp     = c_tab + i0 * J_CAP + j;

    f32x16 acc0 = {};
    f32x16 acc1 = {};

#pragma unroll 2
    for (int r = 0; r < IPW; ++r) {
        const float cj = cp[r * J_CAP];                 // wave-uniform
        float wbuf[8];
#pragma unroll
        for (int e = 0; e < 8; ++e)
            wbuf[e] = wlane[(size_t)r * 16384 + e * 32];  // 2x128B rows per e

        float4 a0 = *(const float4*)(alane0 + r * 16);
        float4 a1 = *(const float4*)(alane0 + r * 16 + 4);
        float4 a2 = *(const float4*)(alane1 + r * 16);
        float4 a3 = *(const float4*)(alane1 + r * 16 + 4);

        short8_t bf, af0, af1;
#pragma unroll
        for (int e = 0; e < 8; ++e) bf[e] = f2bf(wbuf[e] * cj);   // fold c into B
        af0[0] = f2bf(a0.x); af0[1] = f2bf(a0.y); af0[2] = f2bf(a0.z); af0[3] = f2bf(a0.w);
        af0[4] = f2bf(a1.x); af0[5] = f2bf(a1.y); af0[6] = f2bf(a1.z); af0[7] = f2bf(a1.w);
        af1[0] = f2bf(a2.x); af1[1] = f2bf(a2.y); af1[2] = f2bf(a2.z); af1[3] = f2bf(a2.w);
        af1[4] = f2bf(a3.x); af1[5] = f2bf(a3.y); af1[6] = f2bf(a3.z); af1[7] = f2bf(a3.w);

        acc0 = __builtin_amdgcn_mfma_f32_32x32x16_bf16(af0, bf, acc0, 0, 0, 0);
        acc1 = __builtin_amdgcn_mfma_f32_32x32x16_bf16(af1, bf, acc1, 0, 0, 0);
    }

    // ---- epilogue: per-wave C -> LDS (conflict-free), 4-wave reduce, atomics ----
    {
        float* rw = red + wv * 2048;
#pragma unroll
        for (int reg = 0; reg < 16; ++reg) {
            const int b0 = (reg & 3) + 8 * (reg >> 2) + 4 * g;
            rw[b0 * 32 + dn]        = acc0[reg];
            rw[(b0 + 32) * 32 + dn] = acc1[reg];
        }
    }
    __syncthreads();
#pragma unroll
    for (int s = 0; s < 4; ++s) {
        const int o = s * 512 + t * 2;      // b = o>>5, d = o&31 (even), pair (d,d+1)
        float2 v0 = *(const float2*)(red + o);
        float2 v1 = *(const float2*)(red + 2048 + o);
        float2 v2 = *(const float2*)(red + 4096 + o);
        float2 v3 = *(const float2*)(red + 6144 + o);
        const int b = o >> 5, d = o & 31;
        float* dst = s_accum + (size_t)b * (J_CAP * D_DIM) + j * D_DIM + d;
        atomicAdd(dst + 0, v0.x + v1.x + v2.x + v3.x);
        atomicAdd(dst + 1, v0.y + v1.y + v2.y + v3.y);
    }
}

// ---------------- k2: squash per (b,j) row of 32 d's ----------------
__global__ __launch_bounds__(256) void caps_squash_k(const float* __restrict__ s_accum,
                                                     float* __restrict__ out) {
    int tid = blockIdx.x * 256 + threadIdx.x;
    float v = s_accum[tid];
    float sq = v * v;
#pragma unroll
    for (int k = 16; k >= 1; k >>= 1) sq += __shfl_xor(sq, k);
    float scale = sq / (1.0f + sq) / sqrtf(sq);
    out[tid] = v * scale;
}

extern "C" void kernel_launch(void* const* d_in, const int* in_sizes, int n_in,
                              void* d_out, int out_size, void* d_ws, size_t ws_size,
                              hipStream_t stream) {
    const float* inputs = (const float*)d_in[0];
    const float* W      = (const float*)d_in[1];
    const float* bias   = (const float*)d_in[2];
    float* out = (float*)d_out;

    float* c_tab   = (float*)d_ws;           // 65536 f32 = 256 KB
    float* s_accum = c_tab + I_CAP * J_CAP;  // 65536 f32 = 256 KB

    hipMemsetAsync(s_accum, 0, (size_t)B_SZ * J_CAP * D_DIM * sizeof(float), stream);
    caps_softmax_k<<<dim3(256), dim3(256), 0, stream>>>(bias, c_tab);
    caps_main_k<<<dim3(J_CAP * KC), dim3(256), 0, stream>>>(inputs, W, c_tab, s_accum);
    caps_squash_k<<<dim3((B_SZ * J_CAP * D_DIM) / 256), dim3(256), 0, stream>>>(s_accum, out);
}